// Round 4
// baseline (859.055 us; speedup 1.0000x reference)
//
#include <hip/hip_runtime.h>
#include <cstdint>
#include <cstddef>

// ---------------------------------------------------------------------------
// KANAdaptiveFusion: fused = [bases(x) | silu(x)] @ W'^T ; LayerNorm over OUT.
// Round 4: back to the m97 multi-block regime. BM=128,BN=128,BK=64, 4 waves,
// A single-buffered (reg-staged basis) + B double-buffered (global_load_lds),
// 48 KB LDS -> 3 blocks/CU, split-K=2 -> grid 1024. XCD sibling swizzle puts
// the 8 blocks sharing an m-strip on one XCD (x stays L2-hot). Chunk-XOR
// swizzle on both tiles (round-2/3 verified, 0 bank conflicts).
// ---------------------------------------------------------------------------

#define BATCH    16384
#define OUT_DIM  512
#define K_SPLINE 8192
#define KTOT     9216
#define BM       128
#define BN       128
#define BK       64
#define NCHUNK        (KTOT / BK)      // 144
#define SPLINE_CHUNKS (K_SPLINE / BK)  // 128

typedef __attribute__((ext_vector_type(8))) short  short8;
typedef __attribute__((ext_vector_type(4))) float  f32x4;

static __device__ __forceinline__ unsigned short f2bf(float f) {
    unsigned int u = __float_as_uint(f);
    unsigned int r = u + 0x7fffu + ((u >> 16) & 1u);
    return (unsigned short)(r >> 16);
}

// ---------------------------------------------------------------------------
// prep: build W' bf16 (OUT_DIM x KTOT row-major) PRE-SWIZZLED: within each
// 64-element K-block, 8-element chunk cl stored at chunk cl ^ (o&7).
// ---------------------------------------------------------------------------
__global__ void prep_w_kernel(const float* __restrict__ bw,
                              const float* __restrict__ sw,
                              const float* __restrict__ sc,
                              unsigned short* __restrict__ Wp) {
    int t = blockIdx.x * 256 + threadIdx.x;      // < 512 * 1152
    int o = t / 1152;
    int g = t - o * 1152;
    int sz = o & 7;
    unsigned short o8[8];
    size_t dst;
    if (g < 1024) {                 // spline region: i = g, coefs 0..7
        float s = sc[(size_t)o * 1024 + g];
        const float* w = sw + ((size_t)o * 1024 + g) * 8;
        #pragma unroll
        for (int k = 0; k < 8; ++k) o8[k] = f2bf(w[k] * s);
        dst = (size_t)o * KTOT + (size_t)(g >> 3) * 64 + (size_t)(((g & 7) ^ sz)) * 8;
    } else {                        // base region
        int gi = g - 1024;          // 0..127
        const float* w = bw + (size_t)o * 1024 + gi * 8;
        #pragma unroll
        for (int k = 0; k < 8; ++k) o8[k] = f2bf(w[k]);
        dst = (size_t)o * KTOT + K_SPLINE + (size_t)(gi >> 3) * 64 + (size_t)(((gi & 7) ^ sz)) * 8;
    }
    *reinterpret_cast<short8*>(Wp + dst) = *reinterpret_cast<const short8*>(o8);
}

// ---------------------------------------------------------------------------
// GEMM: 128x128 tile, BK=64, 256 threads (4 waves 2x2, 64x64 per wave).
// NSIB = sibling blocks per m-strip (ncol * ksplit) = 8 (split) or 4 (full-K).
// CPS  = K-chunks per block = 72 (split) or 144.
// ---------------------------------------------------------------------------
template<int CPS, int NSIB>
__launch_bounds__(256, 3)
__global__ void kan_gemm_kernel(const float* __restrict__ rgb,
                                const float* __restrict__ tac,
                                const unsigned short* __restrict__ Wp,
                                float* __restrict__ dest_base) {
    __shared__ unsigned short At[BM][BK];        // 16 KB, chunk-swizzled
    __shared__ unsigned short Bt[2][BN][BK];     // 32 KB, chunk-swizzled (via Wp)

    const int tid  = threadIdx.x;
    const int lane = tid & 63;
    const int wid  = tid >> 6;

    // XCD sibling swizzle: the NSIB blocks of one m-strip sit at dispatch-id
    // stride 8 -> same XCD (d%8 round-robin), temporally adjacent.
    const int d    = blockIdx.x;
    const int xcd  = d & 7;
    const int q    = d >> 3;
    const int sib  = q & (NSIB - 1);
    const int gl   = q / NSIB;                   // 0..15
    const int mstrip = xcd * 16 + gl;            // 0..127
    const int ncol = sib & 3;
    const int ksp  = sib >> 2;                   // 0 or 1 (split), always 0 full-K

    const int b0   = mstrip * BM;
    const int n0   = ncol * BN;
    const int wr   = wid & 1;
    const int wc   = wid >> 1;
    const int kc0  = ksp * CPS;
    const int kc1  = kc0 + CPS;
    float* dest = dest_base + (size_t)ksp * BATCH * OUT_DIM;

    f32x4 acc[4][4];
    #pragma unroll
    for (int m = 0; m < 4; ++m)
        #pragma unroll
        for (int n = 0; n < 4; ++n)
            acc[m][n] = (f32x4){0.f, 0.f, 0.f, 0.f};

    short8 sa[4];   // staged A values (next chunk), 1024 elems / 256 threads

    auto stage_regs = [&](int kc) {
        if (kc < SPLINE_CHUNKS) {
            int i0 = kc * 8;
            const float* xs = (i0 < 512) ? rgb : tac;
            int ic = (i0 < 512) ? i0 : (i0 - 512);
            #pragma unroll
            for (int rep = 0; rep < 4; ++rep) {
                int e  = tid + rep * 256;        // 0..1023
                int r  = e >> 3;
                int il = e & 7;
                float x = xs[(size_t)(b0 + r) * 512 + ic + il];
                float tpos = (x + 2.2f) * 2.5f;  // knots -2.2 + 0.4*t
                float fj   = floorf(tpos);
                int   j    = (int)fj;
                bool  inr  = (j >= 0) && (j <= 10);
                float u  = tpos - fj;
                float v  = 1.f - u;
                float u2 = u * u;
                float u3 = u2 * u;
                const float c6 = 1.f / 6.f;
                float n0v = v * v * v * c6;
                float n1v = (3.f * u3 - 6.f * u2 + 4.f) * c6;
                float n2v = (-3.f * u3 + 3.f * u2 + 3.f * u + 1.f) * c6;
                float n3v = u3 * c6;
                unsigned short o8[8];
                #pragma unroll
                for (int k = 0; k < 8; ++k) {
                    int dd = k - j + 3;
                    float val = (dd == 0) ? n0v : (dd == 1) ? n1v
                              : (dd == 2) ? n2v : (dd == 3) ? n3v : 0.f;
                    o8[k] = inr ? f2bf(val) : (unsigned short)0;
                }
                sa[rep] = *reinterpret_cast<const short8*>(o8);
            }
        } else {
            int i0 = (kc - SPLINE_CHUNKS) * 64;
            const float* xs = (i0 < 512) ? rgb : tac;
            int ic = (i0 < 512) ? i0 : (i0 - 512);
            #pragma unroll
            for (int rep = 0; rep < 4; ++rep) {
                int gq = tid + rep * 256;        // 0..1023
                int r  = gq >> 3;
                int c8 = gq & 7;
                const float* xp = xs + (size_t)(b0 + r) * 512 + ic + c8 * 8;
                f32x4 x0 = *reinterpret_cast<const f32x4*>(xp);
                f32x4 x1 = *reinterpret_cast<const f32x4*>(xp + 4);
                unsigned short o8[8];
                #pragma unroll
                for (int qq = 0; qq < 4; ++qq) {
                    float a = x0[qq];
                    o8[qq]     = f2bf(a / (1.f + __expf(-a)));
                    float b = x1[qq];
                    o8[qq + 4] = f2bf(b / (1.f + __expf(-b)));
                }
                sa[rep] = *reinterpret_cast<const short8*>(o8);
            }
        }
    };

    auto write_A = [&]() {
        #pragma unroll
        for (int rep = 0; rep < 4; ++rep) {
            int e = tid + rep * 256;
            int r = e >> 3;
            int c = e & 7;
            *reinterpret_cast<short8*>(&At[r][(c ^ (r & 7)) * 8]) = sa[rep];
        }
    };

    auto gload_B = [&](int kc, int buf) {
        int k0g = kc * BK;
        #pragma unroll
        for (int rp = 0; rp < 4; ++rp) {
            int row0 = wid * 32 + rp * 8;        // wave-uniform LDS base
            const unsigned short* gp =
                Wp + (size_t)(n0 + row0 + (lane >> 3)) * KTOT + k0g + (lane & 7) * 8;
            __builtin_amdgcn_global_load_lds(
                (const __attribute__((address_space(1))) unsigned int*)gp,
                (__attribute__((address_space(3))) unsigned int*)&Bt[buf][row0][0],
                16, 0, 0);
        }
    };

    // ---------------- prologue ----------------
    stage_regs(kc0);
    write_A();
    gload_B(kc0, kc0 & 1);
    asm volatile("s_waitcnt vmcnt(0) lgkmcnt(0)" ::: "memory");
    __syncthreads();

    // ---------------- main loop ----------------
    for (int t = kc0; t < kc1; ++t) {
        const bool more = (t + 1 < kc1);
        if (more) {
            gload_B(t + 1, (t + 1) & 1);  // async into other B buffer
            stage_regs(t + 1);            // VALU; overlaps MFMA below
        }
        #pragma unroll
        for (int ks = 0; ks < 2; ++ks) {
            int cb = ks * 4 + (lane >> 4);
            short8 af[4];
            #pragma unroll
            for (int m = 0; m < 4; ++m) {
                int row = wr * 64 + m * 16 + (lane & 15);
                af[m] = *reinterpret_cast<const short8*>(&At[row][(cb ^ (row & 7)) * 8]);
            }
            #pragma unroll
            for (int n = 0; n < 4; ++n) {
                int row = wc * 64 + n * 16 + (lane & 15);
                short8 bf = *reinterpret_cast<const short8*>(
                    &Bt[t & 1][row][(cb ^ (row & 7)) * 8]);
                #pragma unroll
                for (int m = 0; m < 4; ++m)
                    acc[m][n] = __builtin_amdgcn_mfma_f32_16x16x32_bf16(
                        af[m], bf, acc[m][n], 0, 0, 0);
            }
        }
        __syncthreads();                  // all waves done reading At
        if (more) write_A();              // overwrite A tile for chunk t+1
        asm volatile("s_waitcnt vmcnt(0) lgkmcnt(0)" ::: "memory");
        __syncthreads();
    }

    // ---------------- epilogue: f32 store ----------------
    #pragma unroll
    for (int m = 0; m < 4; ++m) {
        int row = b0 + wr * 64 + m * 16 + ((lane >> 4) << 2);
        #pragma unroll
        for (int n = 0; n < 4; ++n) {
            int col = n0 + wc * 64 + n * 16 + (lane & 15);
            #pragma unroll
            for (int jj = 0; jj < 4; ++jj)
                dest[(size_t)(row + jj) * OUT_DIM + col] = acc[m][n][jj];
        }
    }
}

// ---------------------------------------------------------------------------
// reduce partials + LayerNorm: out = LN(P0 + P1). One wave per row.
// ---------------------------------------------------------------------------
__global__ void reduce_ln_kernel(const float* __restrict__ P0,
                                 const float* __restrict__ P1,
                                 const float* __restrict__ gamma,
                                 const float* __restrict__ beta,
                                 float* __restrict__ out) {
    int row  = blockIdx.x * 4 + (threadIdx.x >> 6);
    int lane = threadIdx.x & 63;
    const float* p0 = P0 + (size_t)row * OUT_DIM;
    const float* p1 = P1 + (size_t)row * OUT_DIM;
    f32x4 a0 = *reinterpret_cast<const f32x4*>(p0 + lane * 4);
    f32x4 a1 = *reinterpret_cast<const f32x4*>(p0 + 256 + lane * 4);
    f32x4 b0 = *reinterpret_cast<const f32x4*>(p1 + lane * 4);
    f32x4 b1 = *reinterpret_cast<const f32x4*>(p1 + 256 + lane * 4);
    f32x4 v0, v1;
    #pragma unroll
    for (int q = 0; q < 4; ++q) { v0[q] = a0[q] + b0[q]; v1[q] = a1[q] + b1[q]; }
    float s = 0.f, ss = 0.f;
    #pragma unroll
    for (int q = 0; q < 4; ++q) {
        s  += v0[q] + v1[q];
        ss += v0[q] * v0[q] + v1[q] * v1[q];
    }
    #pragma unroll
    for (int off = 1; off < 64; off <<= 1) {
        s  += __shfl_xor(s, off);
        ss += __shfl_xor(ss, off);
    }
    float mu  = s * (1.f / 512.f);
    float var = ss * (1.f / 512.f) - mu * mu;
    float rs  = rsqrtf(var + 1e-5f);
    f32x4 g0 = *reinterpret_cast<const f32x4*>(gamma + lane * 4);
    f32x4 g1 = *reinterpret_cast<const f32x4*>(gamma + 256 + lane * 4);
    f32x4 e0 = *reinterpret_cast<const f32x4*>(beta + lane * 4);
    f32x4 e1 = *reinterpret_cast<const f32x4*>(beta + 256 + lane * 4);
    float* po = out + (size_t)row * OUT_DIM;
    f32x4 r0, r1;
    #pragma unroll
    for (int q = 0; q < 4; ++q) {
        r0[q] = (v0[q] - mu) * rs * g0[q] + e0[q];
        r1[q] = (v1[q] - mu) * rs * g1[q] + e1[q];
    }
    *reinterpret_cast<f32x4*>(po + lane * 4)       = r0;
    *reinterpret_cast<f32x4*>(po + 256 + lane * 4) = r1;
}

// ---------------------------------------------------------------------------
// LayerNorm in place (fallback path, no split).
// ---------------------------------------------------------------------------
__global__ void ln_kernel(float* __restrict__ io,
                          const float* __restrict__ gamma,
                          const float* __restrict__ beta) {
    int row  = blockIdx.x * 4 + (threadIdx.x >> 6);
    int lane = threadIdx.x & 63;
    float* p = io + (size_t)row * OUT_DIM;
    f32x4 v0 = *reinterpret_cast<const f32x4*>(p + lane * 4);
    f32x4 v1 = *reinterpret_cast<const f32x4*>(p + 256 + lane * 4);
    float s = 0.f, ss = 0.f;
    #pragma unroll
    for (int q = 0; q < 4; ++q) {
        s  += v0[q] + v1[q];
        ss += v0[q] * v0[q] + v1[q] * v1[q];
    }
    #pragma unroll
    for (int off = 1; off < 64; off <<= 1) {
        s  += __shfl_xor(s, off);
        ss += __shfl_xor(ss, off);
    }
    float mu  = s * (1.f / 512.f);
    float var = ss * (1.f / 512.f) - mu * mu;
    float rs  = rsqrtf(var + 1e-5f);
    f32x4 g0 = *reinterpret_cast<const f32x4*>(gamma + lane * 4);
    f32x4 g1 = *reinterpret_cast<const f32x4*>(gamma + 256 + lane * 4);
    f32x4 e0 = *reinterpret_cast<const f32x4*>(beta + lane * 4);
    f32x4 e1 = *reinterpret_cast<const f32x4*>(beta + 256 + lane * 4);
    f32x4 r0, r1;
    #pragma unroll
    for (int q = 0; q < 4; ++q) {
        r0[q] = (v0[q] - mu) * rs * g0[q] + e0[q];
        r1[q] = (v1[q] - mu) * rs * g1[q] + e1[q];
    }
    *reinterpret_cast<f32x4*>(p + lane * 4)       = r0;
    *reinterpret_cast<f32x4*>(p + 256 + lane * 4) = r1;
}

// ---------------------------------------------------------------------------
extern "C" void kernel_launch(void* const* d_in, const int* in_sizes, int n_in,
                              void* d_out, int out_size, void* d_ws, size_t ws_size,
                              hipStream_t stream) {
    const float* rgb   = (const float*)d_in[0];
    const float* tac   = (const float*)d_in[1];
    const float* bw    = (const float*)d_in[2];
    const float* sw    = (const float*)d_in[3];
    const float* sc    = (const float*)d_in[4];
    const float* gamma = (const float*)d_in[5];
    const float* beta  = (const float*)d_in[6];
    float* out = (float*)d_out;
    unsigned short* Wp = (unsigned short*)d_ws;        // 9.4 MB at ws[0]

    prep_w_kernel<<<2304, 256, 0, stream>>>(bw, sw, sc, Wp);

    const size_t PART = (size_t)BATCH * OUT_DIM * sizeof(float);   // 32 MB
    const size_t POFF = 16ull << 20;                               // 16 MB
    if (ws_size >= POFF + 2 * PART) {
        // split-K=2: grid 1024 (128 mstrip x 4 ncol x 2 ksp), partials in ws
        float* P = (float*)((char*)d_ws + POFF);
        kan_gemm_kernel<NCHUNK / 2, 8><<<1024, 256, 0, stream>>>(rgb, tac, Wp, P);
        reduce_ln_kernel<<<BATCH / 4, 256, 0, stream>>>(
            P, P + (size_t)BATCH * OUT_DIM, gamma, beta, out);
    } else {
        // fallback: full K, grid 512 (128 mstrip x 4 ncol), LN in place
        kan_gemm_kernel<NCHUNK, 4><<<512, 256, 0, stream>>>(rgb, tac, Wp, out);
        ln_kernel<<<BATCH / 4, 256, 0, stream>>>(out, gamma, beta);
    }
}

// Round 5
// 310.914 us; speedup vs baseline: 2.7630x; 2.7630x over previous
//
#include <hip/hip_runtime.h>
#include <cstdint>
#include <cstddef>

// ---------------------------------------------------------------------------
// KANAdaptiveFusion: fused = [bases(x) | silu(x)] @ W'^T ; LayerNorm over OUT.
// Round 5: R3 geometry (BM=128, BN=512, 8 waves, split-K=2, 1x basis work)
// with a fixed schedule: branch-free split loops (spline | base), depth-2 x
// prefetch, write-ahead A staging, raw-barrier + full-drain pairing, and
// MFMA/VALU wave stagger. LDS 144 KB (proven size). Chunk-XOR swizzle
// unchanged (0 conflicts measured).
// ---------------------------------------------------------------------------

#define BATCH    16384
#define OUT_DIM  512
#define KTOT     9216
#define BM       128
#define BK       64
#define NCHUNK        144
#define SPLINE_CHUNKS 128

typedef __attribute__((ext_vector_type(8))) short  short8;
typedef __attribute__((ext_vector_type(4))) float  f32x4;

static __device__ __forceinline__ unsigned short f2bf(float f) {
    unsigned int u = __float_as_uint(f);
    unsigned int r = u + 0x7fffu + ((u >> 16) & 1u);
    return (unsigned short)(r >> 16);
}

// ---------------------------------------------------------------------------
// prep: build W' bf16 (OUT_DIM x KTOT row-major) PRE-SWIZZLED: within each
// 64-element K-block, 8-element chunk cl stored at chunk cl ^ (o&7).
// ---------------------------------------------------------------------------
__global__ void prep_w_kernel(const float* __restrict__ bw,
                              const float* __restrict__ sw,
                              const float* __restrict__ sc,
                              unsigned short* __restrict__ Wp) {
    int t = blockIdx.x * 256 + threadIdx.x;      // < 512 * 1152
    int o = t / 1152;
    int g = t - o * 1152;
    int sz = o & 7;
    unsigned short o8[8];
    size_t dst;
    if (g < 1024) {                 // spline region: i = g, coefs 0..7
        float s = sc[(size_t)o * 1024 + g];
        const float* w = sw + ((size_t)o * 1024 + g) * 8;
        #pragma unroll
        for (int k = 0; k < 8; ++k) o8[k] = f2bf(w[k] * s);
        dst = (size_t)o * KTOT + (size_t)(g >> 3) * 64 + (size_t)(((g & 7) ^ sz)) * 8;
    } else {                        // base region
        int gi = g - 1024;          // 0..127
        const float* w = bw + (size_t)o * 1024 + gi * 8;
        #pragma unroll
        for (int k = 0; k < 8; ++k) o8[k] = f2bf(w[k]);
        dst = (size_t)o * KTOT + (size_t)8192 + (size_t)(gi >> 3) * 64 + (size_t)(((gi & 7) ^ sz)) * 8;
    }
    *reinterpret_cast<short8*>(Wp + dst) = *reinterpret_cast<const short8*>(o8);
}

// ---------------------------------------------------------------------------
// GEMM: 128x512 tile, BK=64, 512 threads (8 waves 2x4; 64x128 per wave,
// 4x8 frags). A single-buffered 16 KB (write-ahead), B dbuf 128 KB.
// ---------------------------------------------------------------------------
template<bool SPLIT>
__launch_bounds__(512, 2)
__global__ void kan_gemm_kernel(const float* __restrict__ rgb,
                                const float* __restrict__ tac,
                                const unsigned short* __restrict__ Wp,
                                float* __restrict__ dest_base) {
    __shared__ unsigned short At[BM][BK];           // 16 KB, chunk-swizzled
    __shared__ unsigned short Bt[2][OUT_DIM][BK];   // 128 KB, chunk-swizzled

    const int tid  = threadIdx.x;
    const int lane = tid & 63;
    const int wid  = tid >> 6;
    const int b0   = blockIdx.x * BM;
    const int wr   = wid & 1;
    const int wc   = wid >> 1;
    const int ksp  = SPLIT ? (int)blockIdx.y : 0;
    const int kc0  = SPLIT ? (ksp ? 72 : 0)             : 0;
    const int kcS  = SPLIT ? (ksp ? SPLINE_CHUNKS : 72) : SPLINE_CHUNKS;
    const int kc1  = SPLIT ? (ksp ? NCHUNK : 72)        : NCHUNK;
    float* dest = dest_base + (size_t)ksp * BATCH * OUT_DIM;

    f32x4 acc[4][8];
    #pragma unroll
    for (int m = 0; m < 4; ++m)
        #pragma unroll
        for (int n = 0; n < 8; ++n)
            acc[m][n] = (f32x4){0.f, 0.f, 0.f, 0.f};

    // ---------------- helpers ----------------
    auto mfma_step = [&](int t) {
        #pragma unroll
        for (int ks = 0; ks < 2; ++ks) {
            int cb = ks * 4 + (lane >> 4);
            short8 af[4];
            #pragma unroll
            for (int m = 0; m < 4; ++m) {
                int row = wr * 64 + m * 16 + (lane & 15);
                af[m] = *reinterpret_cast<const short8*>(&At[row][(cb ^ (row & 7)) * 8]);
            }
            #pragma unroll
            for (int n = 0; n < 8; ++n) {
                int row = wc * 128 + n * 16 + (lane & 15);
                short8 bf = *reinterpret_cast<const short8*>(
                    &Bt[t & 1][row][(cb ^ (row & 7)) * 8]);
                #pragma unroll
                for (int m = 0; m < 4; ++m)
                    acc[m][n] = __builtin_amdgcn_mfma_f32_16x16x32_bf16(
                        af[m], bf, acc[m][n], 0, 0, 0);
            }
        }
    };

    auto load_xs = [&](int c, float* xv) {          // spline-chunk x: 2 floats
        int i0 = c * 8;
        const float* xs = (i0 < 512) ? rgb : tac;
        int ic = (i0 < 512) ? i0 : i0 - 512;
        #pragma unroll
        for (int rep = 0; rep < 2; ++rep) {
            int e = tid + rep * 512;
            xv[rep] = xs[(size_t)(b0 + (e >> 3)) * 512 + ic + (e & 7)];
        }
    };

    auto basis_s = [&](const float* xv, short8* sa) {
        #pragma unroll
        for (int rep = 0; rep < 2; ++rep) {
            float x = xv[rep];
            float tpos = (x + 2.2f) * 2.5f;         // knots -2.2 + 0.4*t
            float fj   = floorf(tpos);
            int   j    = (int)fj;
            bool  inr  = (j >= 0) && (j <= 10);
            float u  = tpos - fj;
            float v  = 1.f - u;
            float u2 = u * u;
            float u3 = u2 * u;
            const float c6 = 1.f / 6.f;
            float n0v = v * v * v * c6;
            float n1v = (3.f * u3 - 6.f * u2 + 4.f) * c6;
            float n2v = (-3.f * u3 + 3.f * u2 + 3.f * u + 1.f) * c6;
            float n3v = u3 * c6;
            unsigned short o8[8];
            #pragma unroll
            for (int k = 0; k < 8; ++k) {
                int dd = k - j + 3;
                float val = (dd == 0) ? n0v : (dd == 1) ? n1v
                          : (dd == 2) ? n2v : (dd == 3) ? n3v : 0.f;
                o8[k] = inr ? f2bf(val) : (unsigned short)0;
            }
            sa[rep] = *reinterpret_cast<const short8*>(o8);
        }
    };

    auto load_xb = [&](int c, f32x4* xb) {          // base-chunk x: 16 floats
        int i0 = (c - SPLINE_CHUNKS) * 64;
        const float* xs = (i0 < 512) ? rgb : tac;
        int ic = (i0 < 512) ? i0 : i0 - 512;
        #pragma unroll
        for (int rep = 0; rep < 2; ++rep) {
            int gq = tid + rep * 512;
            const float* xp = xs + (size_t)(b0 + (gq >> 3)) * 512 + ic + (gq & 7) * 8;
            xb[rep * 2]     = *reinterpret_cast<const f32x4*>(xp);
            xb[rep * 2 + 1] = *reinterpret_cast<const f32x4*>(xp + 4);
        }
    };

    auto basis_b = [&](const f32x4* xb, short8* sa) {
        #pragma unroll
        for (int rep = 0; rep < 2; ++rep) {
            unsigned short o8[8];
            #pragma unroll
            for (int q = 0; q < 4; ++q) {
                float a = xb[rep * 2][q];
                o8[q]     = f2bf(a / (1.f + __expf(-a)));
                float b = xb[rep * 2 + 1][q];
                o8[q + 4] = f2bf(b / (1.f + __expf(-b)));
            }
            sa[rep] = *reinterpret_cast<const short8*>(o8);
        }
    };

    auto write_A = [&](const short8* sa) {
        #pragma unroll
        for (int rep = 0; rep < 2; ++rep) {
            int e = tid + rep * 512;
            int r = e >> 3;
            int c = e & 7;
            *reinterpret_cast<short8*>(&At[r][(c ^ (r & 7)) * 8]) = sa[rep];
        }
    };

    auto gload_B = [&](int kc, int buf) {
        int k0g = kc * BK;
        #pragma unroll
        for (int rp = 0; rp < 8; ++rp) {
            int row0 = wid * 64 + rp * 8;           // wave-uniform LDS base
            const unsigned short* gp =
                Wp + (size_t)(row0 + (lane >> 3)) * KTOT + k0g + (lane & 7) * 8;
            __builtin_amdgcn_global_load_lds(
                (const __attribute__((address_space(1))) unsigned int*)gp,
                (__attribute__((address_space(3))) unsigned int*)&Bt[buf][row0][0],
                16, 0, 0);
        }
    };

    // ================= spline phase: chunks [kc0, kcS) =================
    if (kc0 < kcS) {
        const int lo = kc0, hi = kcS;
        float  xv[2], xq[2], x0[2];
        short8 sa[2];
        load_xs(lo, x0);
        basis_s(x0, sa);
        write_A(sa);
        gload_B(lo, lo & 1);
        load_xs(lo + 1 < hi ? lo + 1 : hi - 1, xv);
        __syncthreads();
        for (int t = lo; t < hi; ++t) {
            int tn = (t + 1 < NCHUNK) ? t + 1 : NCHUNK - 1;
            gload_B(tn, (t + 1) & 1);               // B(t+1): drained at sync
            load_xs(t + 2 < hi ? t + 2 : hi - 1, xq);  // x(t+2): issued early
            if (wid < 4) { mfma_step(t); basis_s(xv, sa); }
            else         { basis_s(xv, sa); mfma_step(t); }
            __builtin_amdgcn_sched_barrier(0);
            __builtin_amdgcn_s_barrier();           // all waves done reading At
            __builtin_amdgcn_sched_barrier(0);
            write_A(sa);                            // A(t+1) write-ahead
            xv[0] = xq[0]; xv[1] = xq[1];
            __syncthreads();                        // publish A(t+1), B(t+1)
        }
    }

    // ================= base phase: chunks [kcS, kc1) =================
    if (kcS < kc1) {
        const int lo = kcS, hi = kc1;
        f32x4  xb[4], xq[4], x0[4];
        short8 sa[2];
        load_xb(lo, x0);
        basis_b(x0, sa);
        write_A(sa);
        if (lo == kc0) gload_B(lo, lo & 1);         // only if no spline phase
        load_xb(lo + 1 < hi ? lo + 1 : hi - 1, xb);
        __syncthreads();
        for (int t = lo; t < hi; ++t) {
            int tn = (t + 1 < NCHUNK) ? t + 1 : NCHUNK - 1;
            gload_B(tn, (t + 1) & 1);
            load_xb(t + 2 < hi ? t + 2 : hi - 1, xq);
            if (wid < 4) { mfma_step(t); basis_b(xb, sa); }
            else         { basis_b(xb, sa); mfma_step(t); }
            __builtin_amdgcn_sched_barrier(0);
            __builtin_amdgcn_s_barrier();
            __builtin_amdgcn_sched_barrier(0);
            write_A(sa);
            #pragma unroll
            for (int q = 0; q < 4; ++q) xb[q] = xq[q];
            __syncthreads();
        }
    }

    // ---------------- epilogue: f32 store ----------------
    #pragma unroll
    for (int m = 0; m < 4; ++m) {
        int row = b0 + wr * 64 + m * 16 + ((lane >> 4) << 2);
        #pragma unroll
        for (int n = 0; n < 8; ++n) {
            int col = wc * 128 + n * 16 + (lane & 15);
            #pragma unroll
            for (int jj = 0; jj < 4; ++jj)
                dest[(size_t)(row + jj) * OUT_DIM + col] = acc[m][n][jj];
        }
    }
}

// ---------------------------------------------------------------------------
// reduce partials + LayerNorm: out = LN(P0 + P1). One wave per row.
// ---------------------------------------------------------------------------
__global__ void reduce_ln_kernel(const float* __restrict__ P0,
                                 const float* __restrict__ P1,
                                 const float* __restrict__ gamma,
                                 const float* __restrict__ beta,
                                 float* __restrict__ out) {
    int row  = blockIdx.x * 4 + (threadIdx.x >> 6);
    int lane = threadIdx.x & 63;
    const float* p0 = P0 + (size_t)row * OUT_DIM;
    const float* p1 = P1 + (size_t)row * OUT_DIM;
    f32x4 a0 = *reinterpret_cast<const f32x4*>(p0 + lane * 4);
    f32x4 a1 = *reinterpret_cast<const f32x4*>(p0 + 256 + lane * 4);
    f32x4 b0 = *reinterpret_cast<const f32x4*>(p1 + lane * 4);
    f32x4 b1 = *reinterpret_cast<const f32x4*>(p1 + 256 + lane * 4);
    f32x4 v0, v1;
    #pragma unroll
    for (int q = 0; q < 4; ++q) { v0[q] = a0[q] + b0[q]; v1[q] = a1[q] + b1[q]; }
    float s = 0.f, ss = 0.f;
    #pragma unroll
    for (int q = 0; q < 4; ++q) {
        s  += v0[q] + v1[q];
        ss += v0[q] * v0[q] + v1[q] * v1[q];
    }
    #pragma unroll
    for (int off = 1; off < 64; off <<= 1) {
        s  += __shfl_xor(s, off);
        ss += __shfl_xor(ss, off);
    }
    float mu  = s * (1.f / 512.f);
    float var = ss * (1.f / 512.f) - mu * mu;
    float rs  = rsqrtf(var + 1e-5f);
    f32x4 g0 = *reinterpret_cast<const f32x4*>(gamma + lane * 4);
    f32x4 g1 = *reinterpret_cast<const f32x4*>(gamma + 256 + lane * 4);
    f32x4 e0 = *reinterpret_cast<const f32x4*>(beta + lane * 4);
    f32x4 e1 = *reinterpret_cast<const f32x4*>(beta + 256 + lane * 4);
    float* po = out + (size_t)row * OUT_DIM;
    f32x4 r0, r1;
    #pragma unroll
    for (int q = 0; q < 4; ++q) {
        r0[q] = (v0[q] - mu) * rs * g0[q] + e0[q];
        r1[q] = (v1[q] - mu) * rs * g1[q] + e1[q];
    }
    *reinterpret_cast<f32x4*>(po + lane * 4)       = r0;
    *reinterpret_cast<f32x4*>(po + 256 + lane * 4) = r1;
}

// ---------------------------------------------------------------------------
// LayerNorm in place (fallback path, no split).
// ---------------------------------------------------------------------------
__global__ void ln_kernel(float* __restrict__ io,
                          const float* __restrict__ gamma,
                          const float* __restrict__ beta) {
    int row  = blockIdx.x * 4 + (threadIdx.x >> 6);
    int lane = threadIdx.x & 63;
    float* p = io + (size_t)row * OUT_DIM;
    f32x4 v0 = *reinterpret_cast<const f32x4*>(p + lane * 4);
    f32x4 v1 = *reinterpret_cast<const f32x4*>(p + 256 + lane * 4);
    float s = 0.f, ss = 0.f;
    #pragma unroll
    for (int q = 0; q < 4; ++q) {
        s  += v0[q] + v1[q];
        ss += v0[q] * v0[q] + v1[q] * v1[q];
    }
    #pragma unroll
    for (int off = 1; off < 64; off <<= 1) {
        s  += __shfl_xor(s, off);
        ss += __shfl_xor(ss, off);
    }
    float mu  = s * (1.f / 512.f);
    float var = ss * (1.f / 512.f) - mu * mu;
    float rs  = rsqrtf(var + 1e-5f);
    f32x4 g0 = *reinterpret_cast<const f32x4*>(gamma + lane * 4);
    f32x4 g1 = *reinterpret_cast<const f32x4*>(gamma + 256 + lane * 4);
    f32x4 e0 = *reinterpret_cast<const f32x4*>(beta + lane * 4);
    f32x4 e1 = *reinterpret_cast<const f32x4*>(beta + 256 + lane * 4);
    f32x4 r0, r1;
    #pragma unroll
    for (int q = 0; q < 4; ++q) {
        r0[q] = (v0[q] - mu) * rs * g0[q] + e0[q];
        r1[q] = (v1[q] - mu) * rs * g1[q] + e1[q];
    }
    *reinterpret_cast<f32x4*>(p + lane * 4)       = r0;
    *reinterpret_cast<f32x4*>(p + 256 + lane * 4) = r1;
}

// ---------------------------------------------------------------------------
extern "C" void kernel_launch(void* const* d_in, const int* in_sizes, int n_in,
                              void* d_out, int out_size, void* d_ws, size_t ws_size,
                              hipStream_t stream) {
    const float* rgb   = (const float*)d_in[0];
    const float* tac   = (const float*)d_in[1];
    const float* bw    = (const float*)d_in[2];
    const float* sw    = (const float*)d_in[3];
    const float* sc    = (const float*)d_in[4];
    const float* gamma = (const float*)d_in[5];
    const float* beta  = (const float*)d_in[6];
    float* out = (float*)d_out;
    unsigned short* Wp = (unsigned short*)d_ws;        // 9.4 MB at ws[0]

    prep_w_kernel<<<2304, 256, 0, stream>>>(bw, sw, sc, Wp);

    const size_t PART = (size_t)BATCH * OUT_DIM * sizeof(float);   // 32 MB
    const size_t POFF = 16ull << 20;                               // 16 MB
    if (ws_size >= POFF + 2 * PART) {
        // split-K=2: grid (128, 2), partials in ws, fused reduce+LN
        float* P = (float*)((char*)d_ws + POFF);
        dim3 g(BATCH / BM, 2);
        kan_gemm_kernel<true><<<g, 512, 0, stream>>>(rgb, tac, Wp, P);
        reduce_ln_kernel<<<BATCH / 4, 256, 0, stream>>>(
            P, P + (size_t)BATCH * OUT_DIM, gamma, beta, out);
    } else {
        // fallback: full K in one pass, LN in place
        dim3 g(BATCH / BM, 1);
        kan_gemm_kernel<false><<<g, 512, 0, stream>>>(rgb, tac, Wp, out);
        ln_kernel<<<BATCH / 4, 256, 0, stream>>>(out, gamma, beta);
    }
}

// Round 6
// 271.275 us; speedup vs baseline: 3.1667x; 1.1461x over previous
//
#include <hip/hip_runtime.h>
#include <cstdint>
#include <cstddef>

// ---------------------------------------------------------------------------
// KANAdaptiveFusion: fused = [bases(x) | silu(x)] @ W'^T ; LayerNorm over OUT.
// Round 6: BM=64, BN=512 (1x basis work), BK=64, SINGLE-buffered B ->
// 72 KB LDS -> 2 blocks/CU (4 waves/SIMD, two independent barrier domains),
// split-K=2 -> grid 512. Keeps: chunk-XOR swizzle (0 conflicts), pre-swizzled
// W', depth-2 x prefetch, write-ahead A, MFMA/VALU wave stagger, phase-split
// branch-free loops.
// ---------------------------------------------------------------------------

#define BATCH    16384
#define OUT_DIM  512
#define KTOT     9216
#define BM       64
#define BK       64
#define NCHUNK        144
#define SPLINE_CHUNKS 128

typedef __attribute__((ext_vector_type(8))) short  short8;
typedef __attribute__((ext_vector_type(4))) float  f32x4;

static __device__ __forceinline__ unsigned short f2bf(float f) {
    unsigned int u = __float_as_uint(f);
    unsigned int r = u + 0x7fffu + ((u >> 16) & 1u);
    return (unsigned short)(r >> 16);
}

// ---------------------------------------------------------------------------
// prep: build W' bf16 (OUT_DIM x KTOT row-major) PRE-SWIZZLED: within each
// 64-element K-block, 8-element chunk cl stored at chunk cl ^ (o&7).
// ---------------------------------------------------------------------------
__global__ void prep_w_kernel(const float* __restrict__ bw,
                              const float* __restrict__ sw,
                              const float* __restrict__ sc,
                              unsigned short* __restrict__ Wp) {
    int t = blockIdx.x * 256 + threadIdx.x;      // < 512 * 1152
    int o = t / 1152;
    int g = t - o * 1152;
    int sz = o & 7;
    unsigned short o8[8];
    size_t dst;
    if (g < 1024) {                 // spline region: i = g, coefs 0..7
        float s = sc[(size_t)o * 1024 + g];
        const float* w = sw + ((size_t)o * 1024 + g) * 8;
        #pragma unroll
        for (int k = 0; k < 8; ++k) o8[k] = f2bf(w[k] * s);
        dst = (size_t)o * KTOT + (size_t)(g >> 3) * 64 + (size_t)(((g & 7) ^ sz)) * 8;
    } else {                        // base region
        int gi = g - 1024;          // 0..127
        const float* w = bw + (size_t)o * 1024 + gi * 8;
        #pragma unroll
        for (int k = 0; k < 8; ++k) o8[k] = f2bf(w[k]);
        dst = (size_t)o * KTOT + (size_t)8192 + (size_t)(gi >> 3) * 64 + (size_t)(((gi & 7) ^ sz)) * 8;
    }
    *reinterpret_cast<short8*>(Wp + dst) = *reinterpret_cast<const short8*>(o8);
}

// ---------------------------------------------------------------------------
// GEMM: 64x512 tile, BK=64, 512 threads (8 waves 2x4; wave tile 32x128 =
// 2x8 frags of 16x16x32). A single 8 KB (write-ahead), B single 64 KB.
// ---------------------------------------------------------------------------
template<bool SPLIT>
__launch_bounds__(512, 4)
__global__ void kan_gemm_kernel(const float* __restrict__ rgb,
                                const float* __restrict__ tac,
                                const unsigned short* __restrict__ Wp,
                                float* __restrict__ dest_base) {
    __shared__ unsigned short At[BM][BK];           //  8 KB, chunk-swizzled
    __shared__ unsigned short Bt[OUT_DIM][BK];      // 64 KB, chunk-swizzled

    const int tid  = threadIdx.x;
    const int lane = tid & 63;
    const int wid  = tid >> 6;
    const int b0   = blockIdx.x * BM;
    const int wr   = wid & 1;                       // 2 m-waves of 32 rows
    const int wc   = wid >> 1;                      // 4 n-waves of 128 cols
    const int ksp  = SPLIT ? (int)blockIdx.y : 0;
    const int kc0  = SPLIT ? (ksp ? 72 : 0)             : 0;
    const int kcS  = SPLIT ? (ksp ? SPLINE_CHUNKS : 72) : SPLINE_CHUNKS;
    const int kc1  = SPLIT ? (ksp ? NCHUNK : 72)        : NCHUNK;
    float* dest = dest_base + (size_t)ksp * BATCH * OUT_DIM;

    f32x4 acc[2][8];
    #pragma unroll
    for (int m = 0; m < 2; ++m)
        #pragma unroll
        for (int n = 0; n < 8; ++n)
            acc[m][n] = (f32x4){0.f, 0.f, 0.f, 0.f};

    // ---------------- helpers ----------------
    auto mfma_step = [&]() {
        #pragma unroll
        for (int ks = 0; ks < 2; ++ks) {
            int cb = ks * 4 + (lane >> 4);
            short8 af[2];
            #pragma unroll
            for (int m = 0; m < 2; ++m) {
                int row = wr * 32 + m * 16 + (lane & 15);
                af[m] = *reinterpret_cast<const short8*>(&At[row][(cb ^ (row & 7)) * 8]);
            }
            #pragma unroll
            for (int n = 0; n < 8; ++n) {
                int row = wc * 128 + n * 16 + (lane & 15);
                short8 bf = *reinterpret_cast<const short8*>(
                    &Bt[row][(cb ^ (row & 7)) * 8]);
                #pragma unroll
                for (int m = 0; m < 2; ++m)
                    acc[m][n] = __builtin_amdgcn_mfma_f32_16x16x32_bf16(
                        af[m], bf, acc[m][n], 0, 0, 0);
            }
        }
    };

    auto load_xs = [&](int c, float& xv) {          // spline chunk: 1 x/thread
        int i0 = c * 8;
        const float* xs = (i0 < 512) ? rgb : tac;
        int ic = (i0 < 512) ? i0 : i0 - 512;
        xv = xs[(size_t)(b0 + (tid >> 3)) * 512 + ic + (tid & 7)];
    };

    auto basis_s = [&](float x, short8& sa) {
        float tpos = (x + 2.2f) * 2.5f;             // knots -2.2 + 0.4*t
        float fj   = floorf(tpos);
        int   j    = (int)fj;
        bool  inr  = (j >= 0) && (j <= 10);
        float u  = tpos - fj;
        float v  = 1.f - u;
        float u2 = u * u;
        float u3 = u2 * u;
        const float c6 = 1.f / 6.f;
        float n0v = v * v * v * c6;
        float n1v = (3.f * u3 - 6.f * u2 + 4.f) * c6;
        float n2v = (-3.f * u3 + 3.f * u2 + 3.f * u + 1.f) * c6;
        float n3v = u3 * c6;
        unsigned short o8[8];
        #pragma unroll
        for (int k = 0; k < 8; ++k) {
            int dd = k - j + 3;
            float val = (dd == 0) ? n0v : (dd == 1) ? n1v
                      : (dd == 2) ? n2v : (dd == 3) ? n3v : 0.f;
            o8[k] = inr ? f2bf(val) : (unsigned short)0;
        }
        sa = *reinterpret_cast<const short8*>(o8);
    };

    auto load_xb = [&](int c, f32x4* xb) {          // base chunk: 8 x/thread
        int i0 = (c - SPLINE_CHUNKS) * 64;
        const float* xs = (i0 < 512) ? rgb : tac;
        int ic = (i0 < 512) ? i0 : i0 - 512;
        const float* xp = xs + (size_t)(b0 + (tid >> 3)) * 512 + ic + (tid & 7) * 8;
        xb[0] = *reinterpret_cast<const f32x4*>(xp);
        xb[1] = *reinterpret_cast<const f32x4*>(xp + 4);
    };

    auto basis_b = [&](const f32x4* xb, short8& sa) {
        unsigned short o8[8];
        #pragma unroll
        for (int q = 0; q < 4; ++q) {
            float a = xb[0][q];
            o8[q]     = f2bf(a / (1.f + __expf(-a)));
            float b = xb[1][q];
            o8[q + 4] = f2bf(b / (1.f + __expf(-b)));
        }
        sa = *reinterpret_cast<const short8*>(o8);
    };

    auto write_A = [&](const short8& sa) {
        int r = tid >> 3;
        int c = tid & 7;
        *reinterpret_cast<short8*>(&At[r][(c ^ (r & 7)) * 8]) = sa;
    };

    auto gload_B = [&](int kc) {
        int k0g = kc * BK;
        #pragma unroll
        for (int rp = 0; rp < 8; ++rp) {
            int row0 = wid * 64 + rp * 8;           // wave-uniform LDS base
            const unsigned short* gp =
                Wp + (size_t)(row0 + (lane >> 3)) * KTOT + k0g + (lane & 7) * 8;
            __builtin_amdgcn_global_load_lds(
                (const __attribute__((address_space(1))) unsigned int*)gp,
                (__attribute__((address_space(3))) unsigned int*)&Bt[row0][0],
                16, 0, 0);
        }
    };

    // ================= spline phase: chunks [kc0, kcS) =================
    if (kc0 < kcS) {
        const int lo = kc0, hi = kcS;
        float  xv, xq, x0;
        short8 sa;
        load_xs(lo, x0);
        basis_s(x0, sa);
        write_A(sa);
        gload_B(lo);
        load_xs(lo + 1 < hi ? lo + 1 : hi - 1, xv);
        __syncthreads();
        for (int t = lo; t < hi; ++t) {
            const bool more = (t + 1 < hi);
            load_xs(t + 2 < hi ? t + 2 : hi - 1, xq);   // x(t+2) issued early
            if (wid < 4) { mfma_step(); basis_s(xv, sa); }
            else         { basis_s(xv, sa); mfma_step(); }
            __builtin_amdgcn_sched_barrier(0);
            __builtin_amdgcn_s_barrier();           // readers done w/ At, Bt
            __builtin_amdgcn_sched_barrier(0);
            if (more) {
                gload_B(t + 1);                     // async refill of Bt
                write_A(sa);                        // A(t+1) write-ahead
            }
            xv = xq;
            __syncthreads();                        // drain + publish
        }
    }

    // ================= base phase: chunks [kcS, kc1) =================
    if (kcS < kc1) {
        const int lo = kcS, hi = kc1;
        f32x4  xb[2], xq[2], x0[2];
        short8 sa;
        load_xb(lo, x0);
        basis_b(x0, sa);
        write_A(sa);
        gload_B(lo);
        load_xb(lo + 1 < hi ? lo + 1 : hi - 1, xb);
        __syncthreads();
        for (int t = lo; t < hi; ++t) {
            const bool more = (t + 1 < hi);
            load_xb(t + 2 < hi ? t + 2 : hi - 1, xq);
            if (wid < 4) { mfma_step(); basis_b(xb, sa); }
            else         { basis_b(xb, sa); mfma_step(); }
            __builtin_amdgcn_sched_barrier(0);
            __builtin_amdgcn_s_barrier();
            __builtin_amdgcn_sched_barrier(0);
            if (more) {
                gload_B(t + 1);
                write_A(sa);
            }
            xb[0] = xq[0]; xb[1] = xq[1];
            __syncthreads();
        }
    }

    // ---------------- epilogue: f32 store ----------------
    #pragma unroll
    for (int m = 0; m < 2; ++m) {
        int row = b0 + wr * 32 + m * 16 + ((lane >> 4) << 2);
        #pragma unroll
        for (int n = 0; n < 8; ++n) {
            int col = wc * 128 + n * 16 + (lane & 15);
            #pragma unroll
            for (int jj = 0; jj < 4; ++jj)
                dest[(size_t)(row + jj) * OUT_DIM + col] = acc[m][n][jj];
        }
    }
}

// ---------------------------------------------------------------------------
// reduce partials + LayerNorm: out = LN(P0 + P1). One wave per row.
// ---------------------------------------------------------------------------
__global__ void reduce_ln_kernel(const float* __restrict__ P0,
                                 const float* __restrict__ P1,
                                 const float* __restrict__ gamma,
                                 const float* __restrict__ beta,
                                 float* __restrict__ out) {
    int row  = blockIdx.x * 4 + (threadIdx.x >> 6);
    int lane = threadIdx.x & 63;
    const float* p0 = P0 + (size_t)row * OUT_DIM;
    const float* p1 = P1 + (size_t)row * OUT_DIM;
    f32x4 a0 = *reinterpret_cast<const f32x4*>(p0 + lane * 4);
    f32x4 a1 = *reinterpret_cast<const f32x4*>(p0 + 256 + lane * 4);
    f32x4 b0 = *reinterpret_cast<const f32x4*>(p1 + lane * 4);
    f32x4 b1 = *reinterpret_cast<const f32x4*>(p1 + 256 + lane * 4);
    f32x4 v0, v1;
    #pragma unroll
    for (int q = 0; q < 4; ++q) { v0[q] = a0[q] + b0[q]; v1[q] = a1[q] + b1[q]; }
    float s = 0.f, ss = 0.f;
    #pragma unroll
    for (int q = 0; q < 4; ++q) {
        s  += v0[q] + v1[q];
        ss += v0[q] * v0[q] + v1[q] * v1[q];
    }
    #pragma unroll
    for (int off = 1; off < 64; off <<= 1) {
        s  += __shfl_xor(s, off);
        ss += __shfl_xor(ss, off);
    }
    float mu  = s * (1.f / 512.f);
    float var = ss * (1.f / 512.f) - mu * mu;
    float rs  = rsqrtf(var + 1e-5f);
    f32x4 g0 = *reinterpret_cast<const f32x4*>(gamma + lane * 4);
    f32x4 g1 = *reinterpret_cast<const f32x4*>(gamma + 256 + lane * 4);
    f32x4 e0 = *reinterpret_cast<const f32x4*>(beta + lane * 4);
    f32x4 e1 = *reinterpret_cast<const f32x4*>(beta + 256 + lane * 4);
    float* po = out + (size_t)row * OUT_DIM;
    f32x4 r0, r1;
    #pragma unroll
    for (int q = 0; q < 4; ++q) {
        r0[q] = (v0[q] - mu) * rs * g0[q] + e0[q];
        r1[q] = (v1[q] - mu) * rs * g1[q] + e1[q];
    }
    *reinterpret_cast<f32x4*>(po + lane * 4)       = r0;
    *reinterpret_cast<f32x4*>(po + 256 + lane * 4) = r1;
}

// ---------------------------------------------------------------------------
// LayerNorm in place (fallback path, no split).
// ---------------------------------------------------------------------------
__global__ void ln_kernel(float* __restrict__ io,
                          const float* __restrict__ gamma,
                          const float* __restrict__ beta) {
    int row  = blockIdx.x * 4 + (threadIdx.x >> 6);
    int lane = threadIdx.x & 63;
    float* p = io + (size_t)row * OUT_DIM;
    f32x4 v0 = *reinterpret_cast<const f32x4*>(p + lane * 4);
    f32x4 v1 = *reinterpret_cast<const f32x4*>(p + 256 + lane * 4);
    float s = 0.f, ss = 0.f;
    #pragma unroll
    for (int q = 0; q < 4; ++q) {
        s  += v0[q] + v1[q];
        ss += v0[q] * v0[q] + v1[q] * v1[q];
    }
    #pragma unroll
    for (int off = 1; off < 64; off <<= 1) {
        s  += __shfl_xor(s, off);
        ss += __shfl_xor(ss, off);
    }
    float mu  = s * (1.f / 512.f);
    float var = ss * (1.f / 512.f) - mu * mu;
    float rs  = rsqrtf(var + 1e-5f);
    f32x4 g0 = *reinterpret_cast<const f32x4*>(gamma + lane * 4);
    f32x4 g1 = *reinterpret_cast<const f32x4*>(gamma + 256 + lane * 4);
    f32x4 e0 = *reinterpret_cast<const f32x4*>(beta + lane * 4);
    f32x4 e1 = *reinterpret_cast<const f32x4*>(beta + 256 + lane * 4);
    f32x4 r0, r1;
    #pragma unroll
    for (int q = 0; q < 4; ++q) {
        r0[q] = (v0[q] - mu) * rs * g0[q] + e0[q];
        r1[q] = (v1[q] - mu) * rs * g1[q] + e1[q];
    }
    *reinterpret_cast<f32x4*>(p + lane * 4)       = r0;
    *reinterpret_cast<f32x4*>(p + 256 + lane * 4) = r1;
}

// ---------------------------------------------------------------------------
extern "C" void kernel_launch(void* const* d_in, const int* in_sizes, int n_in,
                              void* d_out, int out_size, void* d_ws, size_t ws_size,
                              hipStream_t stream) {
    const float* rgb   = (const float*)d_in[0];
    const float* tac   = (const float*)d_in[1];
    const float* bw    = (const float*)d_in[2];
    const float* sw    = (const float*)d_in[3];
    const float* sc    = (const float*)d_in[4];
    const float* gamma = (const float*)d_in[5];
    const float* beta  = (const float*)d_in[6];
    float* out = (float*)d_out;
    unsigned short* Wp = (unsigned short*)d_ws;        // 9.4 MB at ws[0]

    prep_w_kernel<<<2304, 256, 0, stream>>>(bw, sw, sc, Wp);

    const size_t PART = (size_t)BATCH * OUT_DIM * sizeof(float);   // 32 MB
    const size_t POFF = 16ull << 20;                               // 16 MB
    if (ws_size >= POFF + 2 * PART) {
        // split-K=2: grid (256, 2) = 512 blocks = 2/CU, partials in ws
        float* P = (float*)((char*)d_ws + POFF);
        dim3 g(BATCH / BM, 2);
        kan_gemm_kernel<true><<<g, 512, 0, stream>>>(rgb, tac, Wp, P);
        reduce_ln_kernel<<<BATCH / 4, 256, 0, stream>>>(
            P, P + (size_t)BATCH * OUT_DIM, gamma, beta, out);
    } else {
        // fallback: full K in one pass, LN in place
        dim3 g(BATCH / BM, 1);
        kan_gemm_kernel<false><<<g, 512, 0, stream>>>(rgb, tac, Wp, out);
        ln_kernel<<<BATCH / 4, 256, 0, stream>>>(out, gamma, beta);
    }
}

// Round 7
// 190.994 us; speedup vs baseline: 4.4978x; 1.4203x over previous
//
#include <hip/hip_runtime.h>
#include <cstdint>
#include <cstddef>

// ---------------------------------------------------------------------------
// KANAdaptiveFusion: fused = [bases(x) | silu(x)] @ W'^T ; LayerNorm over OUT.
// Round 7: BM=128, BN=512, BK=64, 1024 threads (16 waves 2x8, 64x64/wave:
// minimal LDS-read amplification). B double-buffered (128 KB) + A single
// (16 KB) = 144 KB. Raw 2-barrier loop, x-before-B load order so the B
// prefetch drains only at the end-of-iteration vmcnt(0) (full window).
// Basis via cvt_pk + 128-bit shift placement (~45 ops vs ~104). Split-K=2,
// grid (128,2) = 256 = 1 block/CU. Chunk-XOR swizzle unchanged (0 conflicts).
// ---------------------------------------------------------------------------

#define BATCH    16384
#define OUT_DIM  512
#define KTOT     9216
#define BM       128
#define BK       64
#define NCHUNK        144
#define SPLINE_CHUNKS 128

typedef __attribute__((ext_vector_type(8))) short  short8;
typedef __attribute__((ext_vector_type(4))) float  f32x4;

static __device__ __forceinline__ unsigned short f2bf(float f) {
    unsigned int u = __float_as_uint(f);
    unsigned int r = u + 0x7fffu + ((u >> 16) & 1u);
    return (unsigned short)(r >> 16);
}

// ---------------------------------------------------------------------------
// prep: W' bf16 (OUT_DIM x KTOT row-major) PRE-SWIZZLED: within each 64-elem
// K-block, 8-element chunk cl stored at chunk cl ^ (o&7).  (unchanged, proven)
// ---------------------------------------------------------------------------
__global__ void prep_w_kernel(const float* __restrict__ bw,
                              const float* __restrict__ sw,
                              const float* __restrict__ sc,
                              unsigned short* __restrict__ Wp) {
    int t = blockIdx.x * 256 + threadIdx.x;      // < 512 * 1152
    int o = t / 1152;
    int g = t - o * 1152;
    int sz = o & 7;
    unsigned short o8[8];
    size_t dst;
    if (g < 1024) {                 // spline region: i = g, coefs 0..7
        float s = sc[(size_t)o * 1024 + g];
        const float* w = sw + ((size_t)o * 1024 + g) * 8;
        #pragma unroll
        for (int k = 0; k < 8; ++k) o8[k] = f2bf(w[k] * s);
        dst = (size_t)o * KTOT + (size_t)(g >> 3) * 64 + (size_t)(((g & 7) ^ sz)) * 8;
    } else {                        // base region
        int gi = g - 1024;          // 0..127
        const float* w = bw + (size_t)o * 1024 + gi * 8;
        #pragma unroll
        for (int k = 0; k < 8; ++k) o8[k] = f2bf(w[k]);
        dst = (size_t)o * KTOT + (size_t)8192 + (size_t)(gi >> 3) * 64 + (size_t)(((gi & 7) ^ sz)) * 8;
    }
    *reinterpret_cast<short8*>(Wp + dst) = *reinterpret_cast<const short8*>(o8);
}

// ---------------------------------------------------------------------------
// basis8: cubic B-spline bases of x packed as 4 u32 (8 bf16), via cvt_pk +
// variable 128-bit shift placement. Verified vs the select-chain version.
// ---------------------------------------------------------------------------
static __device__ __forceinline__ void basis8(float x, unsigned* out) {
    float tpos = (x + 2.2f) * 2.5f;          // knots -2.2 + 0.4*t
    float fj   = floorf(tpos);
    int   j    = (int)fj;
    float u  = tpos - fj;
    float v  = 1.f - u;
    float u2 = u * u;
    float u3 = u2 * u;
    const float c6 = 1.f / 6.f;
    float n0 = v * v * v * c6;
    float n1 = (3.f * u3 - 6.f * u2 + 4.f) * c6;
    float n2 = (-3.f * u3 + 3.f * u2 + 3.f * u + 1.f) * c6;
    float n3 = u3 * c6;
    unsigned p0, p1;
    asm("v_cvt_pk_bf16_f32 %0, %1, %2" : "=v"(p0) : "v"(n0), "v"(n1));
    asm("v_cvt_pk_bf16_f32 %0, %1, %2" : "=v"(p1) : "v"(n2), "v"(n3));
    int sh = (j << 4) - 48;                  // bf16-slot shift *16
    int c  = sh & 16;
    int w  = (sh - c) >> 5;                  // signed word shift
    unsigned long long P = ((unsigned long long)p1 << 32) | p0;
    unsigned long long T = P << c;
    unsigned t0 = (unsigned)T;
    unsigned t1 = (unsigned)(T >> 32);
    unsigned t2 = c ? (p1 >> 16) : 0u;
    #pragma unroll
    for (int i = 0; i < 4; ++i) {
        unsigned r = 0u;
        r = (w == i    ) ? t0 : r;
        r = (w == i - 1) ? t1 : r;
        r = (w == i - 2) ? t2 : r;
        out[i] = r;
    }
}

// ---------------------------------------------------------------------------
// GEMM: 128x512 tile, BK=64, 1024 threads (16 waves 2x8; 64x64 per wave).
// ---------------------------------------------------------------------------
template<bool SPLIT>
__launch_bounds__(1024, 4)
__global__ void kan_gemm_kernel(const float* __restrict__ rgb,
                                const float* __restrict__ tac,
                                const unsigned short* __restrict__ Wp,
                                float* __restrict__ dest_base) {
    __shared__ unsigned short At[BM][BK];           // 16 KB, chunk-swizzled
    __shared__ unsigned short Bt[2][OUT_DIM][BK];   // 128 KB, chunk-swizzled

    const int tid  = threadIdx.x;
    const int lane = tid & 63;
    const int wid  = tid >> 6;
    const int b0   = blockIdx.x * BM;
    const int wr   = wid & 1;                       // 2 m-waves (64 rows)
    const int wc   = wid >> 1;                      // 8 n-waves (64 cols)
    const int ksp  = SPLIT ? (int)blockIdx.y : 0;
    const int kc0  = SPLIT ? (ksp ? 72 : 0)             : 0;
    const int kcS  = SPLIT ? (ksp ? SPLINE_CHUNKS : 72) : SPLINE_CHUNKS;
    const int kc1  = SPLIT ? (ksp ? NCHUNK : 72)        : NCHUNK;
    float* dest = dest_base + (size_t)ksp * BATCH * OUT_DIM;

    const int ar = tid >> 3;                        // A-staging row 0..127
    const int af_ = tid & 7;                        // A-staging chunk 0..7

    f32x4 acc[4][4];
    #pragma unroll
    for (int m = 0; m < 4; ++m)
        #pragma unroll
        for (int n = 0; n < 4; ++n)
            acc[m][n] = (f32x4){0.f, 0.f, 0.f, 0.f};

    auto mfma_step = [&](int buf) {
        #pragma unroll
        for (int ks = 0; ks < 2; ++ks) {
            int cb = ks * 4 + (lane >> 4);
            short8 afr[4];
            #pragma unroll
            for (int m = 0; m < 4; ++m) {
                int row = wr * 64 + m * 16 + (lane & 15);
                afr[m] = *reinterpret_cast<const short8*>(&At[row][(cb ^ (row & 7)) * 8]);
            }
            #pragma unroll
            for (int n = 0; n < 4; ++n) {
                int row = wc * 64 + n * 16 + (lane & 15);
                short8 bfr = *reinterpret_cast<const short8*>(
                    &Bt[buf][row][(cb ^ (row & 7)) * 8]);
                #pragma unroll
                for (int m = 0; m < 4; ++m)
                    acc[m][n] = __builtin_amdgcn_mfma_f32_16x16x32_bf16(
                        afr[m], bfr, acc[m][n], 0, 0, 0);
            }
        }
    };

    auto loadx_s = [&](int c) -> float {            // spline: 1 x/thread
        int i0 = c * 8;
        const float* xs = (i0 < 512) ? rgb : tac;
        int ic = i0 & 511;
        return xs[(size_t)(b0 + ar) * 512 + ic + af_];
    };

    auto loadx_b = [&](int c, f32x4& xa, f32x4& xb) {  // base: 8 x/thread
        int i0 = (c - SPLINE_CHUNKS) * 64;
        const float* xs = (i0 < 512) ? rgb : tac;
        int ic = i0 & 511;
        const float* xp = xs + (size_t)(b0 + ar) * 512 + ic + af_ * 8;
        xa = *reinterpret_cast<const f32x4*>(xp);
        xb = *reinterpret_cast<const f32x4*>(xp + 4);
    };

    auto silupack = [&](const f32x4& xa, const f32x4& xb, unsigned* o) {
        float s[8];
        #pragma unroll
        for (int q = 0; q < 4; ++q) {
            float a = xa[q]; s[q]     = a / (1.f + __expf(-a));
            float b = xb[q]; s[q + 4] = b / (1.f + __expf(-b));
        }
        #pragma unroll
        for (int q = 0; q < 4; ++q)
            asm("v_cvt_pk_bf16_f32 %0, %1, %2"
                : "=v"(o[q]) : "v"(s[2 * q]), "v"(s[2 * q + 1]));
    };

    auto writeA = [&](const unsigned* o4) {
        *reinterpret_cast<short8*>(&At[ar][(af_ ^ (ar & 7)) * 8]) =
            *reinterpret_cast<const short8*>(o4);
    };

    auto gload_B = [&](int kc, int buf) {
        int k0g = kc * BK;
        #pragma unroll
        for (int rp = 0; rp < 4; ++rp) {
            int row0 = wid * 32 + rp * 8;           // wave-uniform LDS base
            const unsigned short* gp =
                Wp + (size_t)(row0 + (lane >> 3)) * KTOT + k0g + (lane & 7) * 8;
            __builtin_amdgcn_global_load_lds(
                (const __attribute__((address_space(1))) unsigned int*)gp,
                (__attribute__((address_space(3))) unsigned int*)&Bt[buf][row0][0],
                16, 0, 0);
        }
    };

    // ---------------- spline prologue: chunk kc0 into buf 0 ----------------
    {
        float x0 = loadx_s(kc0);
        gload_B(kc0, 0);
        unsigned o4[4];
        basis8(x0, o4);
        writeA(o4);
        asm volatile("s_waitcnt vmcnt(0) lgkmcnt(0)" ::: "memory");
        __builtin_amdgcn_s_barrier();
        asm volatile("" ::: "memory");
    }

    // ---------------- spline loop: [kc0, kcS) ----------------
    for (int t = kc0; t < kcS; ++t) {
        const int  buf   = (t - kc0) & 1;
        const bool moreB = (t + 1 < kc1);
        const bool moreA = (t + 1 < kcS);
        float xn = 0.f;
        if (moreA) xn = loadx_s(t + 1);             // x first (older in queue)
        asm volatile("" ::: "memory");
        if (moreB) gload_B(t + 1, buf ^ 1);         // B prefetch (stays in flight)
        mfma_step(buf);
        unsigned o4[4];
        if (moreA) basis8(xn, o4);                  // auto-waits x only (counted)
        __builtin_amdgcn_sched_barrier(0);
        __builtin_amdgcn_s_barrier();               // #1: At free
        asm volatile("" ::: "memory");
        if (moreA) writeA(o4);
        asm volatile("s_waitcnt vmcnt(0) lgkmcnt(0)" ::: "memory");
        __builtin_amdgcn_sched_barrier(0);
        __builtin_amdgcn_s_barrier();               // #2: publish A(t+1), B(t+1)
        asm volatile("" ::: "memory");
    }

    // ---------------- base phase: [kcS, kc1) ----------------
    if (kcS < kc1) {
        {   // base prologue: A(kcS); B(kcS) already prefetched+fenced
            f32x4 xa, xb;
            loadx_b(kcS, xa, xb);
            unsigned o4[4];
            silupack(xa, xb, o4);
            writeA(o4);
            asm volatile("s_waitcnt vmcnt(0) lgkmcnt(0)" ::: "memory");
            __builtin_amdgcn_s_barrier();
            asm volatile("" ::: "memory");
        }
        for (int t = kcS; t < kc1; ++t) {
            const int  buf   = (t - kc0) & 1;
            const bool more  = (t + 1 < kc1);
            f32x4 xa, xb;
            if (more) loadx_b(t + 1, xa, xb);
            asm volatile("" ::: "memory");
            if (more) gload_B(t + 1, buf ^ 1);
            mfma_step(buf);
            unsigned o4[4];
            if (more) silupack(xa, xb, o4);
            __builtin_amdgcn_sched_barrier(0);
            __builtin_amdgcn_s_barrier();           // #1: At free
            asm volatile("" ::: "memory");
            if (more) writeA(o4);
            asm volatile("s_waitcnt vmcnt(0) lgkmcnt(0)" ::: "memory");
            __builtin_amdgcn_sched_barrier(0);
            __builtin_amdgcn_s_barrier();           // #2: publish
            asm volatile("" ::: "memory");
        }
    }

    // ---------------- epilogue: f32 partial store ----------------
    #pragma unroll
    for (int m = 0; m < 4; ++m) {
        int row = b0 + wr * 64 + m * 16 + ((lane >> 4) << 2);
        #pragma unroll
        for (int n = 0; n < 4; ++n) {
            int col = wc * 64 + n * 16 + (lane & 15);
            #pragma unroll
            for (int jj = 0; jj < 4; ++jj)
                dest[(size_t)(row + jj) * OUT_DIM + col] = acc[m][n][jj];
        }
    }
}

// ---------------------------------------------------------------------------
// reduce partials + LayerNorm: out = LN(P0 + P1). One wave per row.
// ---------------------------------------------------------------------------
__global__ void reduce_ln_kernel(const float* __restrict__ P0,
                                 const float* __restrict__ P1,
                                 const float* __restrict__ gamma,
                                 const float* __restrict__ beta,
                                 float* __restrict__ out) {
    int row  = blockIdx.x * 4 + (threadIdx.x >> 6);
    int lane = threadIdx.x & 63;
    const float* p0 = P0 + (size_t)row * OUT_DIM;
    const float* p1 = P1 + (size_t)row * OUT_DIM;
    f32x4 a0 = *reinterpret_cast<const f32x4*>(p0 + lane * 4);
    f32x4 a1 = *reinterpret_cast<const f32x4*>(p0 + 256 + lane * 4);
    f32x4 b0 = *reinterpret_cast<const f32x4*>(p1 + lane * 4);
    f32x4 b1 = *reinterpret_cast<const f32x4*>(p1 + 256 + lane * 4);
    f32x4 v0, v1;
    #pragma unroll
    for (int q = 0; q < 4; ++q) { v0[q] = a0[q] + b0[q]; v1[q] = a1[q] + b1[q]; }
    float s = 0.f, ss = 0.f;
    #pragma unroll
    for (int q = 0; q < 4; ++q) {
        s  += v0[q] + v1[q];
        ss += v0[q] * v0[q] + v1[q] * v1[q];
    }
    #pragma unroll
    for (int off = 1; off < 64; off <<= 1) {
        s  += __shfl_xor(s, off);
        ss += __shfl_xor(ss, off);
    }
    float mu  = s * (1.f / 512.f);
    float var = ss * (1.f / 512.f) - mu * mu;
    float rs  = rsqrtf(var + 1e-5f);
    f32x4 g0 = *reinterpret_cast<const f32x4*>(gamma + lane * 4);
    f32x4 g1 = *reinterpret_cast<const f32x4*>(gamma + 256 + lane * 4);
    f32x4 e0 = *reinterpret_cast<const f32x4*>(beta + lane * 4);
    f32x4 e1 = *reinterpret_cast<const f32x4*>(beta + 256 + lane * 4);
    float* po = out + (size_t)row * OUT_DIM;
    f32x4 r0, r1;
    #pragma unroll
    for (int q = 0; q < 4; ++q) {
        r0[q] = (v0[q] - mu) * rs * g0[q] + e0[q];
        r1[q] = (v1[q] - mu) * rs * g1[q] + e1[q];
    }
    *reinterpret_cast<f32x4*>(po + lane * 4)       = r0;
    *reinterpret_cast<f32x4*>(po + 256 + lane * 4) = r1;
}

// ---------------------------------------------------------------------------
// LayerNorm in place (fallback path, no split).
// ---------------------------------------------------------------------------
__global__ void ln_kernel(float* __restrict__ io,
                          const float* __restrict__ gamma,
                          const float* __restrict__ beta) {
    int row  = blockIdx.x * 4 + (threadIdx.x >> 6);
    int lane = threadIdx.x & 63;
    float* p = io + (size_t)row * OUT_DIM;
    f32x4 v0 = *reinterpret_cast<const f32x4*>(p + lane * 4);
    f32x4 v1 = *reinterpret_cast<const f32x4*>(p + 256 + lane * 4);
    float s = 0.f, ss = 0.f;
    #pragma unroll
    for (int q = 0; q < 4; ++q) {
        s  += v0[q] + v1[q];
        ss += v0[q] * v0[q] + v1[q] * v1[q];
    }
    #pragma unroll
    for (int off = 1; off < 64; off <<= 1) {
        s  += __shfl_xor(s, off);
        ss += __shfl_xor(ss, off);
    }
    float mu  = s * (1.f / 512.f);
    float var = ss * (1.f / 512.f) - mu * mu;
    float rs  = rsqrtf(var + 1e-5f);
    f32x4 g0 = *reinterpret_cast<const f32x4*>(gamma + lane * 4);
    f32x4 g1 = *reinterpret_cast<const f32x4*>(gamma + 256 + lane * 4);
    f32x4 e0 = *reinterpret_cast<const f32x4*>(beta + lane * 4);
    f32x4 e1 = *reinterpret_cast<const f32x4*>(beta + 256 + lane * 4);
    f32x4 r0, r1;
    #pragma unroll
    for (int q = 0; q < 4; ++q) {
        r0[q] = (v0[q] - mu) * rs * g0[q] + e0[q];
        r1[q] = (v1[q] - mu) * rs * g1[q] + e1[q];
    }
    *reinterpret_cast<f32x4*>(p + lane * 4)       = r0;
    *reinterpret_cast<f32x4*>(p + 256 + lane * 4) = r1;
}

// ---------------------------------------------------------------------------
extern "C" void kernel_launch(void* const* d_in, const int* in_sizes, int n_in,
                              void* d_out, int out_size, void* d_ws, size_t ws_size,
                              hipStream_t stream) {
    const float* rgb   = (const float*)d_in[0];
    const float* tac   = (const float*)d_in[1];
    const float* bw    = (const float*)d_in[2];
    const float* sw    = (const float*)d_in[3];
    const float* sc    = (const float*)d_in[4];
    const float* gamma = (const float*)d_in[5];
    const float* beta  = (const float*)d_in[6];
    float* out = (float*)d_out;
    unsigned short* Wp = (unsigned short*)d_ws;        // 9.4 MB at ws[0]

    prep_w_kernel<<<2304, 256, 0, stream>>>(bw, sw, sc, Wp);

    const size_t PART = (size_t)BATCH * OUT_DIM * sizeof(float);   // 32 MB
    const size_t POFF = 16ull << 20;                               // 16 MB
    if (ws_size >= POFF + 2 * PART) {
        // split-K=2: grid (128, 2) = 256 blocks = 1/CU, partials in ws
        float* P = (float*)((char*)d_ws + POFF);
        dim3 g(BATCH / BM, 2);
        kan_gemm_kernel<true><<<g, 1024, 0, stream>>>(rgb, tac, Wp, P);
        reduce_ln_kernel<<<BATCH / 4, 256, 0, stream>>>(
            P, P + (size_t)BATCH * OUT_DIM, gamma, beta, out);
    } else {
        // fallback: full K in one pass, LN in place
        dim3 g(BATCH / BM, 1);
        kan_gemm_kernel<false><<<g, 1024, 0, stream>>>(rgb, tac, Wp, out);
        ln_kernel<<<BATCH / 4, 256, 0, stream>>>(out, gamma, beta);
    }
}

// Round 8
// 184.795 us; speedup vs baseline: 4.6487x; 1.0335x over previous
//
#include <hip/hip_runtime.h>
#include <cstdint>
#include <cstddef>

// ---------------------------------------------------------------------------
// KANAdaptiveFusion: fused = [bases(x) | silu(x)] @ W'^T ; LayerNorm over OUT.
// Round 8: R7 + T4 counted-vmcnt pipeline. A double-buffered (2x16 KB) so
// writeA overlaps MFMA; B(t+2) issued right after barrier #A and waited with
// vmcnt(4) (never 0) -> B prefetch spans a full iteration. LDS = 160 KB
// exactly. Split-K=2, 1024 thr (16 waves 2x8, 64x64/wave), chunk-XOR swizzle.
// ---------------------------------------------------------------------------

#define BATCH    16384
#define OUT_DIM  512
#define KTOT     9216
#define BM       128
#define BK       64
#define NCHUNK        144
#define SPLINE_CHUNKS 128

typedef __attribute__((ext_vector_type(8))) short  short8;
typedef __attribute__((ext_vector_type(4))) float  f32x4;

static __device__ __forceinline__ unsigned short f2bf(float f) {
    unsigned int u = __float_as_uint(f);
    unsigned int r = u + 0x7fffu + ((u >> 16) & 1u);
    return (unsigned short)(r >> 16);
}

// ---------------------------------------------------------------------------
// prep: W' bf16 (OUT_DIM x KTOT row-major) PRE-SWIZZLED: within each 64-elem
// K-block, 8-element chunk cl stored at chunk cl ^ (o&7).  (proven)
// ---------------------------------------------------------------------------
__global__ void prep_w_kernel(const float* __restrict__ bw,
                              const float* __restrict__ sw,
                              const float* __restrict__ sc,
                              unsigned short* __restrict__ Wp) {
    int t = blockIdx.x * 256 + threadIdx.x;      // < 512 * 1152
    int o = t / 1152;
    int g = t - o * 1152;
    int sz = o & 7;
    unsigned short o8[8];
    size_t dst;
    if (g < 1024) {                 // spline region: i = g, coefs 0..7
        float s = sc[(size_t)o * 1024 + g];
        const float* w = sw + ((size_t)o * 1024 + g) * 8;
        #pragma unroll
        for (int k = 0; k < 8; ++k) o8[k] = f2bf(w[k] * s);
        dst = (size_t)o * KTOT + (size_t)(g >> 3) * 64 + (size_t)(((g & 7) ^ sz)) * 8;
    } else {                        // base region
        int gi = g - 1024;          // 0..127
        const float* w = bw + (size_t)o * 1024 + gi * 8;
        #pragma unroll
        for (int k = 0; k < 8; ++k) o8[k] = f2bf(w[k]);
        dst = (size_t)o * KTOT + (size_t)8192 + (size_t)(gi >> 3) * 64 + (size_t)(((gi & 7) ^ sz)) * 8;
    }
    *reinterpret_cast<short8*>(Wp + dst) = *reinterpret_cast<const short8*>(o8);
}

// ---------------------------------------------------------------------------
// basis8: cubic B-spline bases packed as 4 u32 (8 bf16). (proven in R7)
// ---------------------------------------------------------------------------
static __device__ __forceinline__ void basis8(float x, unsigned* out) {
    float tpos = (x + 2.2f) * 2.5f;          // knots -2.2 + 0.4*t
    float fj   = floorf(tpos);
    int   j    = (int)fj;
    float u  = tpos - fj;
    float v  = 1.f - u;
    float u2 = u * u;
    float u3 = u2 * u;
    const float c6 = 1.f / 6.f;
    float n0 = v * v * v * c6;
    float n1 = (3.f * u3 - 6.f * u2 + 4.f) * c6;
    float n2 = (-3.f * u3 + 3.f * u2 + 3.f * u + 1.f) * c6;
    float n3 = u3 * c6;
    unsigned p0, p1;
    asm("v_cvt_pk_bf16_f32 %0, %1, %2" : "=v"(p0) : "v"(n0), "v"(n1));
    asm("v_cvt_pk_bf16_f32 %0, %1, %2" : "=v"(p1) : "v"(n2), "v"(n3));
    int sh = (j << 4) - 48;                  // bf16-slot shift *16
    int c  = sh & 16;
    int w  = (sh - c) >> 5;                  // signed word shift
    unsigned long long P = ((unsigned long long)p1 << 32) | p0;
    unsigned long long T = P << c;
    unsigned t0 = (unsigned)T;
    unsigned t1 = (unsigned)(T >> 32);
    unsigned t2 = c ? (p1 >> 16) : 0u;
    #pragma unroll
    for (int i = 0; i < 4; ++i) {
        unsigned r = 0u;
        r = (w == i    ) ? t0 : r;
        r = (w == i - 1) ? t1 : r;
        r = (w == i - 2) ? t2 : r;
        out[i] = r;
    }
}

// ---------------------------------------------------------------------------
// GEMM: 128x512 tile, BK=64, 1024 threads (16 waves 2x8; 64x64 per wave).
// A dbuf 2x16 KB + B dbuf 2x64 KB = 160 KB.
// ---------------------------------------------------------------------------
template<bool SPLIT>
__launch_bounds__(1024, 4)
__global__ void kan_gemm_kernel(const float* __restrict__ rgb,
                                const float* __restrict__ tac,
                                const unsigned short* __restrict__ Wp,
                                float* __restrict__ dest_base) {
    __shared__ unsigned short At[2][BM][BK];        //  32 KB, chunk-swizzled
    __shared__ unsigned short Bt[2][OUT_DIM][BK];   // 128 KB, chunk-swizzled

    const int tid  = threadIdx.x;
    const int lane = tid & 63;
    const int wid  = tid >> 6;
    const int b0   = blockIdx.x * BM;
    const int wr   = wid & 1;                       // 2 m-waves (64 rows)
    const int wc   = wid >> 1;                      // 8 n-waves (64 cols)
    const int ksp  = SPLIT ? (int)blockIdx.y : 0;
    const int kc0  = SPLIT ? (ksp ? 72 : 0)             : 0;
    const int kcS  = SPLIT ? (ksp ? SPLINE_CHUNKS : 72) : SPLINE_CHUNKS;
    const int kc1  = SPLIT ? (ksp ? NCHUNK : 72)        : NCHUNK;
    float* dest = dest_base + (size_t)ksp * BATCH * OUT_DIM;

    const int ar  = tid >> 3;                       // A-staging row 0..127
    const int af_ = tid & 7;                        // A-staging chunk 0..7

    f32x4 acc[4][4];
    #pragma unroll
    for (int m = 0; m < 4; ++m)
        #pragma unroll
        for (int n = 0; n < 4; ++n)
            acc[m][n] = (f32x4){0.f, 0.f, 0.f, 0.f};

    auto mfma_step = [&](int ab, int bb) {
        #pragma unroll
        for (int ks = 0; ks < 2; ++ks) {
            int cb = ks * 4 + (lane >> 4);
            short8 afr[4];
            #pragma unroll
            for (int m = 0; m < 4; ++m) {
                int row = wr * 64 + m * 16 + (lane & 15);
                afr[m] = *reinterpret_cast<const short8*>(&At[ab][row][(cb ^ (row & 7)) * 8]);
            }
            #pragma unroll
            for (int n = 0; n < 4; ++n) {
                int row = wc * 64 + n * 16 + (lane & 15);
                short8 bfr = *reinterpret_cast<const short8*>(
                    &Bt[bb][row][(cb ^ (row & 7)) * 8]);
                #pragma unroll
                for (int m = 0; m < 4; ++m)
                    acc[m][n] = __builtin_amdgcn_mfma_f32_16x16x32_bf16(
                        afr[m], bfr, acc[m][n], 0, 0, 0);
            }
        }
    };

    auto loadx_s = [&](int c) -> float {            // spline: 1 x/thread
        int i0 = c * 8;
        const float* xs = (i0 < 512) ? rgb : tac;
        int ic = i0 & 511;
        return xs[(size_t)(b0 + ar) * 512 + ic + af_];
    };

    auto loadx_b = [&](int c, f32x4& xa, f32x4& xb) {  // base: 8 x/thread
        int i0 = (c - SPLINE_CHUNKS) * 64;
        const float* xs = (i0 < 512) ? rgb : tac;
        int ic = i0 & 511;
        const float* xp = xs + (size_t)(b0 + ar) * 512 + ic + af_ * 8;
        xa = *reinterpret_cast<const f32x4*>(xp);
        xb = *reinterpret_cast<const f32x4*>(xp + 4);
    };

    auto silupack = [&](const f32x4& xa, const f32x4& xb, unsigned* o) {
        float s[8];
        #pragma unroll
        for (int q = 0; q < 4; ++q) {
            float a = xa[q]; s[q]     = a / (1.f + __expf(-a));
            float b = xb[q]; s[q + 4] = b / (1.f + __expf(-b));
        }
        #pragma unroll
        for (int q = 0; q < 4; ++q)
            asm("v_cvt_pk_bf16_f32 %0, %1, %2"
                : "=v"(o[q]) : "v"(s[2 * q]), "v"(s[2 * q + 1]));
    };

    auto writeA = [&](const unsigned* o4, int ab) {
        *reinterpret_cast<short8*>(&At[ab][ar][(af_ ^ (ar & 7)) * 8]) =
            *reinterpret_cast<const short8*>(o4);
    };

    auto gload_B = [&](int kc, int buf) {
        int k0g = kc * BK;
        #pragma unroll
        for (int rp = 0; rp < 4; ++rp) {
            int row0 = wid * 32 + rp * 8;           // wave-uniform LDS base
            const unsigned short* gp =
                Wp + (size_t)(row0 + (lane >> 3)) * KTOT + k0g + (lane & 7) * 8;
            __builtin_amdgcn_global_load_lds(
                (const __attribute__((address_space(1))) unsigned int*)gp,
                (__attribute__((address_space(3))) unsigned int*)&Bt[buf][row0][0],
                16, 0, 0);
        }
    };

    // ---------------- prologue (kc0 is always a spline chunk) --------------
    gload_B(kc0, 0);
    gload_B(kc0 + 1 < kc1 ? kc0 + 1 : kc1 - 1, 1);
    {
        float x0 = loadx_s(kc0);
        unsigned o4[4];
        basis8(x0, o4);
        writeA(o4, 0);
    }
    float xn = (kc0 + 1 < kcS) ? loadx_s(kc0 + 1) : 0.f;
    asm volatile("s_waitcnt vmcnt(4) lgkmcnt(0)" ::: "memory");
    __builtin_amdgcn_sched_barrier(0);
    __builtin_amdgcn_s_barrier();
    __builtin_amdgcn_sched_barrier(0);

    // ---------------- spline loop: [kc0, kcS) ----------------
    for (int t = kc0; t < kcS; ++t) {
        const int  buf   = (t - kc0) & 1;           // B(t)/A(t) parity
        const bool moreA = (t + 1 < kcS);
        unsigned o4[4];
        if (moreA) {                                 // A(t+1): VALU || MFMA
            basis8(xn, o4);
            writeA(o4, buf ^ 1);
        }
        if (t + 2 < kcS) xn = loadx_s(t + 2);        // x(t+2) issued early
        mfma_step(buf, buf);
        __builtin_amdgcn_sched_barrier(0);
        __builtin_amdgcn_s_barrier();                // #A: buffers t free
        __builtin_amdgcn_sched_barrier(0);
        int tn = (t + 2 < kc1) ? t + 2 : kc1 - 1;
        gload_B(tn, buf);                            // B(t+2) into freed buf
        asm volatile("s_waitcnt vmcnt(4) lgkmcnt(0)" ::: "memory"); // B(t+1) done
        __builtin_amdgcn_sched_barrier(0);
        __builtin_amdgcn_s_barrier();                // #B: publish t+1
        __builtin_amdgcn_sched_barrier(0);
    }

    // ---------------- base phase: [kcS, kc1) ----------------
    if (kcS < kc1) {
        f32x4 xa{}, xb{};
        {   // stage A(kcS); B(kcS) already published, B(kcS+1) in flight
            f32x4 a0, b0;
            loadx_b(kcS, a0, b0);
            unsigned o4[4];
            silupack(a0, b0, o4);
            writeA(o4, (kcS - kc0) & 1);
            if (kcS + 1 < kc1) loadx_b(kcS + 1, xa, xb);
            asm volatile("s_waitcnt lgkmcnt(0)" ::: "memory");
            __builtin_amdgcn_sched_barrier(0);
            __builtin_amdgcn_s_barrier();            // publish A(kcS)
            __builtin_amdgcn_sched_barrier(0);
        }
        for (int t = kcS; t < kc1; ++t) {
            const int  buf   = (t - kc0) & 1;
            const bool moreA = (t + 1 < kc1);
            unsigned o4[4];
            if (moreA) {
                silupack(xa, xb, o4);
                writeA(o4, buf ^ 1);
            }
            f32x4 na, nb;
            const bool moreX = (t + 2 < kc1);
            if (moreX) loadx_b(t + 2, na, nb);
            mfma_step(buf, buf);
            __builtin_amdgcn_sched_barrier(0);
            __builtin_amdgcn_s_barrier();            // #A
            __builtin_amdgcn_sched_barrier(0);
            int tn = moreX ? t + 2 : kc1 - 1;
            gload_B(tn, buf);
            asm volatile("s_waitcnt vmcnt(4) lgkmcnt(0)" ::: "memory");
            __builtin_amdgcn_sched_barrier(0);
            __builtin_amdgcn_s_barrier();            // #B
            __builtin_amdgcn_sched_barrier(0);
            if (moreX) { xa = na; xb = nb; }
        }
    }

    // ---------------- epilogue: f32 partial store ----------------
    #pragma unroll
    for (int m = 0; m < 4; ++m) {
        int row = b0 + wr * 64 + m * 16 + ((lane >> 4) << 2);
        #pragma unroll
        for (int n = 0; n < 4; ++n) {
            int col = wc * 64 + n * 16 + (lane & 15);
            #pragma unroll
            for (int jj = 0; jj < 4; ++jj)
                dest[(size_t)(row + jj) * OUT_DIM + col] = acc[m][n][jj];
        }
    }
}

// ---------------------------------------------------------------------------
// reduce partials + LayerNorm: out = LN(P0 + P1). One wave per row.
// ---------------------------------------------------------------------------
__global__ void reduce_ln_kernel(const float* __restrict__ P0,
                                 const float* __restrict__ P1,
                                 const float* __restrict__ gamma,
                                 const float* __restrict__ beta,
                                 float* __restrict__ out) {
    int row  = blockIdx.x * 4 + (threadIdx.x >> 6);
    int lane = threadIdx.x & 63;
    const float* p0 = P0 + (size_t)row * OUT_DIM;
    const float* p1 = P1 + (size_t)row * OUT_DIM;
    f32x4 a0 = *reinterpret_cast<const f32x4*>(p0 + lane * 4);
    f32x4 a1 = *reinterpret_cast<const f32x4*>(p0 + 256 + lane * 4);
    f32x4 b0 = *reinterpret_cast<const f32x4*>(p1 + lane * 4);
    f32x4 b1 = *reinterpret_cast<const f32x4*>(p1 + 256 + lane * 4);
    f32x4 v0, v1;
    #pragma unroll
    for (int q = 0; q < 4; ++q) { v0[q] = a0[q] + b0[q]; v1[q] = a1[q] + b1[q]; }
    float s = 0.f, ss = 0.f;
    #pragma unroll
    for (int q = 0; q < 4; ++q) {
        s  += v0[q] + v1[q];
        ss += v0[q] * v0[q] + v1[q] * v1[q];
    }
    #pragma unroll
    for (int off = 1; off < 64; off <<= 1) {
        s  += __shfl_xor(s, off);
        ss += __shfl_xor(ss, off);
    }
    float mu  = s * (1.f / 512.f);
    float var = ss * (1.f / 512.f) - mu * mu;
    float rs  = rsqrtf(var + 1e-5f);
    f32x4 g0 = *reinterpret_cast<const f32x4*>(gamma + lane * 4);
    f32x4 g1 = *reinterpret_cast<const f32x4*>(gamma + 256 + lane * 4);
    f32x4 e0 = *reinterpret_cast<const f32x4*>(beta + lane * 4);
    f32x4 e1 = *reinterpret_cast<const f32x4*>(beta + 256 + lane * 4);
    float* po = out + (size_t)row * OUT_DIM;
    f32x4 r0, r1;
    #pragma unroll
    for (int q = 0; q < 4; ++q) {
        r0[q] = (v0[q] - mu) * rs * g0[q] + e0[q];
        r1[q] = (v1[q] - mu) * rs * g1[q] + e1[q];
    }
    *reinterpret_cast<f32x4*>(po + lane * 4)       = r0;
    *reinterpret_cast<f32x4*>(po + 256 + lane * 4) = r1;
}

// ---------------------------------------------------------------------------
// LayerNorm in place (fallback path, no split).
// ---------------------------------------------------------------------------
__global__ void ln_kernel(float* __restrict__ io,
                          const float* __restrict__ gamma,
                          const float* __restrict__ beta) {
    int row  = blockIdx.x * 4 + (threadIdx.x >> 6);
    int lane = threadIdx.x & 63;
    float* p = io + (size_t)row * OUT_DIM;
    f32x4 v0 = *reinterpret_cast<const f32x4*>(p + lane * 4);
    f32x4 v1 = *reinterpret_cast<const f32x4*>(p + 256 + lane * 4);
    float s = 0.f, ss = 0.f;
    #pragma unroll
    for (int q = 0; q < 4; ++q) {
        s  += v0[q] + v1[q];
        ss += v0[q] * v0[q] + v1[q] * v1[q];
    }
    #pragma unroll
    for (int off = 1; off < 64; off <<= 1) {
        s  += __shfl_xor(s, off);
        ss += __shfl_xor(ss, off);
    }
    float mu  = s * (1.f / 512.f);
    float var = ss * (1.f / 512.f) - mu * mu;
    float rs  = rsqrtf(var + 1e-5f);
    f32x4 g0 = *reinterpret_cast<const f32x4*>(gamma + lane * 4);
    f32x4 g1 = *reinterpret_cast<const f32x4*>(gamma + 256 + lane * 4);
    f32x4 e0 = *reinterpret_cast<const f32x4*>(beta + lane * 4);
    f32x4 e1 = *reinterpret_cast<const f32x4*>(beta + 256 + lane * 4);
    f32x4 r0, r1;
    #pragma unroll
    for (int q = 0; q < 4; ++q) {
        r0[q] = (v0[q] - mu) * rs * g0[q] + e0[q];
        r1[q] = (v1[q] - mu) * rs * g1[q] + e1[q];
    }
    *reinterpret_cast<f32x4*>(p + lane * 4)       = r0;
    *reinterpret_cast<f32x4*>(p + 256 + lane * 4) = r1;
}

// ---------------------------------------------------------------------------
extern "C" void kernel_launch(void* const* d_in, const int* in_sizes, int n_in,
                              void* d_out, int out_size, void* d_ws, size_t ws_size,
                              hipStream_t stream) {
    const float* rgb   = (const float*)d_in[0];
    const float* tac   = (const float*)d_in[1];
    const float* bw    = (const float*)d_in[2];
    const float* sw    = (const float*)d_in[3];
    const float* sc    = (const float*)d_in[4];
    const float* gamma = (const float*)d_in[5];
    const float* beta  = (const float*)d_in[6];
    float* out = (float*)d_out;
    unsigned short* Wp = (unsigned short*)d_ws;        // 9.4 MB at ws[0]

    prep_w_kernel<<<2304, 256, 0, stream>>>(bw, sw, sc, Wp);

    const size_t PART = (size_t)BATCH * OUT_DIM * sizeof(float);   // 32 MB
    const size_t POFF = 16ull << 20;                               // 16 MB
    if (ws_size >= POFF + 2 * PART) {
        // split-K=2: grid (128, 2) = 256 blocks = 1/CU, partials in ws
        float* P = (float*)((char*)d_ws + POFF);
        dim3 g(BATCH / BM, 2);
        kan_gemm_kernel<true><<<g, 1024, 0, stream>>>(rgb, tac, Wp, P);
        reduce_ln_kernel<<<BATCH / 4, 256, 0, stream>>>(
            P, P + (size_t)BATCH * OUT_DIM, gamma, beta, out);
    } else {
        // fallback: full K in one pass, LN in place
        dim3 g(BATCH / BM, 1);
        kan_gemm_kernel<false><<<g, 1024, 0, stream>>>(rgb, tac, Wp, out);
        ln_kernel<<<BATCH / 4, 256, 0, stream>>>(out, gamma, beta);
    }
}